// Round 1
// 1861.566 us; speedup vs baseline: 1.2469x; 1.2469x over previous
//
#include <hip/hip_runtime.h>
#include <cstddef>
#include <cstdint>

// VisionExperts on MI355X — bf16 MFMA rewrite (m97-style 128x128/BK=32 tiles).
//   E0: S=448 P=14 C=1024 G=32 T=1024 K=588->Kp608   (no resizes)
//   E1: S=336 P=14 C=768  G=24 T=576  K=588->Kp608   (img 448->336, feat 24->32)
//   E2: S=448 P=32 C=1152 G=14 T=196  K=3072         (feat 14->32)
// This revision: patch gather lifted out of the tower GEMM into a one-shot
// vectorized im2col (k_im2col) producing dense [token][Kp] bf16 A-matrices;
// tower GEMM now stages BOTH operands via global_load_lds (same as k_proj).
// Previous version's in-GEMM 2-byte scalar gather was latency-bound
// (MfmaUtil 6%, HBM 10%, VALU 15% on the 555us E0 tower dispatch).

#define HID 1024

typedef __bf16 bf16x8 __attribute__((ext_vector_type(8)));
typedef float f32x4 __attribute__((ext_vector_type(4)));

__device__ __forceinline__ unsigned short f2bf(float f) {
  union { float f; unsigned u; } v; v.f = f;
  unsigned r = v.u + 0x7fffu + ((v.u >> 16) & 1u);  // RNE
  return (unsigned short)(r >> 16);
}
__device__ __forceinline__ float bf2f(unsigned h) {
  union { unsigned u; float f; } v; v.u = h << 16;
  return v.f;
}
__device__ __forceinline__ void gld16(const unsigned short* g, unsigned short* l) {
  auto gp = (const __attribute__((address_space(1))) unsigned int*)(const void*)g;
  auto lp = (__attribute__((address_space(3))) unsigned int*)(void*)l;
  __builtin_amdgcn_global_load_lds(gp, lp, 16, 0, 0);
}

// ---------------------------------------------------------------- small prep kernels
__global__ void k_weights(const int* __restrict__ sel, const float* __restrict__ rw,
                          float* __restrict__ w3) {
  int b = threadIdx.x;
  if (b < 64) {
    float w0 = 0.f, w1 = 0.f, w2 = 0.f;
    for (int k = 0; k < 2; ++k) {
      int e = sel[b * 2 + k];
      float r = rw[b * 2 + k];
      if (e == 0) w0 += r; else if (e == 1) w1 += r; else w2 += r;
    }
    w3[b * 3 + 0] = w0; w3[b * 3 + 1] = w1; w3[b * 3 + 2] = w2;
  }
}

__global__ void k_tables(int* __restrict__ koff, int* __restrict__ rowoff,
                         int4* __restrict__ stok, float4* __restrict__ wco,
                         int S, int P, int G, int T, int bch, int K, int Kp) {
  int idx = blockIdx.x * 256 + threadIdx.x;
  if (idx < Kp) {
    if (idx < K) {
      int pp = P * P;
      int ch = idx / pp;
      int r = idx - ch * pp;
      int py = r / P;
      int px = r - py * P;
      koff[idx] = ch * S * S + py * S + px;
    } else koff[idx] = 0;
  }
  int nro = bch * T;
  if (idx < nro) {
    int bl = idx / T;
    int t = idx - bl * T;
    int gy = t / G;
    int gx = t - gy * G;
    rowoff[idx] = bl * 3 * S * S + gy * P * S + gx * P;
  }
  if (idx < 1024) {
    int oy = idx >> 5, ox = idx & 31;
    float sc = (float)(G - 1) / 31.0f;
    float fy = oy * sc, fx = ox * sc;
    int y0 = (int)floorf(fy), x0 = (int)floorf(fx);
    float ty = fy - y0, tx = fx - x0;
    int y1 = min(y0 + 1, G - 1), x1 = min(x0 + 1, G - 1);
    stok[idx] = make_int4(y0 * G + x0, y0 * G + x1, y1 * G + x0, y1 * G + x1);
    wco[idx] = make_float4((1.f - ty) * (1.f - tx), (1.f - ty) * tx,
                           ty * (1.f - tx), ty * tx);
  }
}

__global__ void k_img2bf(const float* __restrict__ x, unsigned short* __restrict__ o, int n4) {
  int idx = blockIdx.x * 256 + threadIdx.x;
  if (idx < n4) {
    float4 v = ((const float4*)x)[idx];
    ushort4 r;
    r.x = f2bf(v.x); r.y = f2bf(v.y); r.z = f2bf(v.z); r.w = f2bf(v.w);
    ((ushort4*)o)[idx] = r;
  }
}

__global__ void k_resize_img(const float* __restrict__ x, unsigned short* __restrict__ o,
                             int total) {
  int idx = blockIdx.x * 256 + threadIdx.x;
  if (idx >= total) return;
  int ox = idx % 336;
  int t = idx / 336;
  int oy = t % 336;
  int bc = t / 336;
  const float sc = 447.0f / 335.0f;
  float fy = oy * sc, fx = ox * sc;
  int y0 = (int)floorf(fy), x0 = (int)floorf(fx);
  float ty = fy - y0, tx = fx - x0;
  int y1 = min(y0 + 1, 447), x1 = min(x0 + 1, 447);
  const float* p = x + (size_t)bc * 448 * 448;
  float v00 = p[y0 * 448 + x0], v01 = p[y0 * 448 + x1];
  float v10 = p[y1 * 448 + x0], v11 = p[y1 * 448 + x1];
  float r0 = v00 * (1.f - ty) + v10 * ty;
  float r1 = v01 * (1.f - ty) + v11 * ty;
  o[idx] = f2bf(r0 * (1.f - tx) + r1 * tx);
}

// W [K][N] fp32 -> Wp [N][Kp] bf16 (zero-pad K..Kp), 32x32 LDS tile transpose
__global__ void k_pack_w(const float* __restrict__ W, unsigned short* __restrict__ Wp,
                         int K, int N, int Kp) {
  __shared__ float t[32][33];
  int kb = blockIdx.x * 32, nb = blockIdx.y * 32;
  int tx = threadIdx.x & 31, ty = threadIdx.x >> 5;
#pragma unroll
  for (int r = 0; r < 32; r += 8) {
    int k = kb + ty + r, n = nb + tx;
    t[ty + r][tx] = (k < K) ? W[(size_t)k * N + n] : 0.f;
  }
  __syncthreads();
#pragma unroll
  for (int r = 0; r < 32; r += 8) {
    int n = nb + ty + r, k = kb + tx;
    if (k < Kp) Wp[(size_t)n * Kp + k] = f2bf(t[tx][ty + r]);
  }
}

// ---------------------------------------------------------------- im2col (patch gather)
// Ap[m][k] = img[rowoff[m] + koff[k]] for m<M, k<K; zero elsewhere (rows padded to Mp).
// x2-vectorized along k: patch rows (runs of P) start at even k AND even pixel offsets,
// so (k, k+1) with even k always map to an aligned contiguous pixel pair.
__global__ void k_im2col(const unsigned short* __restrict__ img,
                         unsigned short* __restrict__ Ap,
                         const int* __restrict__ rowoff, const int* __restrict__ koff,
                         int M, int K, int Kp) {
  int k2 = (blockIdx.y * 256 + threadIdx.x) * 2;
  if (k2 >= Kp) return;
  int m = blockIdx.x;
  unsigned v = 0;
  if (m < M && k2 < K)
    v = *(const unsigned*)(const void*)&img[rowoff[m] + koff[k2]];
  *(unsigned*)(void*)&Ap[(size_t)m * Kp + k2] = v;
}

// ---------------------------------------------------------------- tower GEMM (bf16 MFMA)
// Fp[m][n] = bf16( sum_k Ap[m][k] * Wp[n][k] + bias[n] )   — both operands DMA-staged.
// Grid covers Mp/128 row-blocks; rows [M,Mp) are zero-padded, so no M guards needed.
__global__ __launch_bounds__(256) void k_tower(
    const unsigned short* __restrict__ Ap, const unsigned short* __restrict__ Wp,
    const float* __restrict__ bias, unsigned short* __restrict__ Fp,
    int N, int Kp) {
  __shared__ __align__(16) unsigned short As[128 * 32];
  __shared__ __align__(16) unsigned short Bs[128 * 32];
  int tid = threadIdx.x, wave = tid >> 6, lane = tid & 63;
  int n0 = blockIdx.x * 128, m0 = blockIdx.y * 128;

  const unsigned short* arow0 = Ap + (size_t)(m0 + (tid >> 2)) * Kp + (tid & 3) * 8;
  const unsigned short* arow1 = arow0 + (size_t)64 * Kp;
  const unsigned short* wrow0 = Wp + (size_t)(n0 + (tid >> 2)) * Kp + (tid & 3) * 8;
  const unsigned short* wrow1 = wrow0 + (size_t)64 * Kp;
  unsigned short* AsW0 = As + wave * 512;
  unsigned short* AsW1 = As + 2048 + wave * 512;
  unsigned short* BsW0 = Bs + wave * 512;
  unsigned short* BsW1 = Bs + 2048 + wave * 512;

  int wm = (wave >> 1) << 6, wn = (wave & 1) << 6;
  int fm = lane & 15, fq = (lane >> 4) << 3;
  f32x4 acc[4][4] = {};

  for (int kb = 0; kb < Kp; kb += 32) {
    __syncthreads();
    gld16(arow0 + kb, AsW0);
    gld16(arow1 + kb, AsW1);
    gld16(wrow0 + kb, BsW0);
    gld16(wrow1 + kb, BsW1);
    __syncthreads();
    bf16x8 af[4], bfr[4];
#pragma unroll
    for (int i = 0; i < 4; ++i) af[i] = *(const bf16x8*)&As[(wm + i * 16 + fm) * 32 + fq];
#pragma unroll
    for (int j = 0; j < 4; ++j) bfr[j] = *(const bf16x8*)&Bs[(wn + j * 16 + fm) * 32 + fq];
#pragma unroll
    for (int i = 0; i < 4; ++i)
#pragma unroll
      for (int j = 0; j < 4; ++j)
        acc[i][j] = __builtin_amdgcn_mfma_f32_16x16x32_bf16(af[i], bfr[j], acc[i][j], 0, 0, 0);
  }

  int mq = (lane >> 4) << 2;
#pragma unroll
  for (int i = 0; i < 4; ++i) {
    int mbase = m0 + wm + i * 16 + mq;
#pragma unroll
    for (int j = 0; j < 4; ++j) {
      int n = n0 + wn + j * 16 + fm;
      float bsv = bias[n];
      f32x4 v = acc[i][j];
#pragma unroll
      for (int r = 0; r < 4; ++r)
        Fp[(size_t)(mbase + r) * N + n] = f2bf(v[r] + bsv);
    }
  }
}

// ---------------------------------------------------------------- feature-grid resize (bf16)
__global__ void k_feat_resize(const unsigned short* __restrict__ C1,
                              unsigned short* __restrict__ F,
                              const int4* __restrict__ stok, const float4* __restrict__ wco,
                              int Tsrc, int C) {
  int bt = blockIdx.x;
  int bl = bt >> 10, t = bt & 1023;
  int4 s = stok[t];
  float4 w = wco[t];
  const unsigned* b32 = (const unsigned*)(C1 + (size_t)bl * Tsrc * C);
  unsigned* o32 = (unsigned*)(F + (size_t)bt * C);
  int C2 = C >> 1;
  int r0 = s.x * C2, r1 = s.y * C2, r2 = s.z * C2, r3 = s.w * C2;
  for (int c = threadIdx.x; c < C2; c += 256) {
    unsigned p0 = b32[r0 + c], p1 = b32[r1 + c], p2 = b32[r2 + c], p3 = b32[r3 + c];
    float lo = w.x * bf2f(p0 & 0xffffu) + w.y * bf2f(p1 & 0xffffu) +
               w.z * bf2f(p2 & 0xffffu) + w.w * bf2f(p3 & 0xffffu);
    float hi = w.x * bf2f(p0 >> 16) + w.y * bf2f(p1 >> 16) +
               w.z * bf2f(p2 >> 16) + w.w * bf2f(p3 >> 16);
    o32[c] = (unsigned)f2bf(lo) | ((unsigned)f2bf(hi) << 16);
  }
}

// ---------------------------------------------------------------- projector GEMM (bf16 MFMA)
// mode 0: out = wgt*(A@W + bias)   (zero-fills when wgt==0)
// mode 1: out += wgt*(A@W + bias)  (returns when wgt==0)
__global__ __launch_bounds__(256) void k_proj(
    const unsigned short* __restrict__ Ap, const unsigned short* __restrict__ Wp,
    const float* __restrict__ bias, float* __restrict__ out,
    const float* __restrict__ w3, int b0, int e, int K, int mode) {
  __shared__ __align__(16) unsigned short As[128 * 32];
  __shared__ __align__(16) unsigned short Bs[128 * 32];
  int tid = threadIdx.x, wave = tid >> 6, lane = tid & 63;
  int n0 = blockIdx.x * 128, m0 = blockIdx.y * 128;
  float wgt = w3[(b0 + (m0 >> 10)) * 3 + e];
  float* obase = out + ((size_t)b0 * 1024 + (size_t)m0) * HID + n0;
  if (wgt == 0.f) {
    if (mode == 0) {
      float4 z = make_float4(0.f, 0.f, 0.f, 0.f);
      for (int idx = tid; idx < 128 * 32; idx += 256) {
        int rr = idx >> 5, cc = (idx & 31) << 2;
        *(float4*)&obase[(size_t)rr * HID + cc] = z;
      }
    }
    return;
  }
  const unsigned short* arow0 = Ap + (size_t)(m0 + (tid >> 2)) * K + (tid & 3) * 8;
  const unsigned short* arow1 = arow0 + (size_t)64 * K;
  const unsigned short* wrow0 = Wp + (size_t)(n0 + (tid >> 2)) * K + (tid & 3) * 8;
  const unsigned short* wrow1 = wrow0 + (size_t)64 * K;
  unsigned short* AsW0 = As + wave * 512;
  unsigned short* AsW1 = As + 2048 + wave * 512;
  unsigned short* BsW0 = Bs + wave * 512;
  unsigned short* BsW1 = Bs + 2048 + wave * 512;

  int wm = (wave >> 1) << 6, wn = (wave & 1) << 6;
  int fm = lane & 15, fq = (lane >> 4) << 3;
  f32x4 acc[4][4] = {};

  for (int kb = 0; kb < K; kb += 32) {
    __syncthreads();
    gld16(arow0 + kb, AsW0);
    gld16(arow1 + kb, AsW1);
    gld16(wrow0 + kb, BsW0);
    gld16(wrow1 + kb, BsW1);
    __syncthreads();
    bf16x8 af[4], bfr[4];
#pragma unroll
    for (int i = 0; i < 4; ++i) af[i] = *(const bf16x8*)&As[(wm + i * 16 + fm) * 32 + fq];
#pragma unroll
    for (int j = 0; j < 4; ++j) bfr[j] = *(const bf16x8*)&Bs[(wn + j * 16 + fm) * 32 + fq];
#pragma unroll
    for (int i = 0; i < 4; ++i)
#pragma unroll
      for (int j = 0; j < 4; ++j)
        acc[i][j] = __builtin_amdgcn_mfma_f32_16x16x32_bf16(af[i], bfr[j], acc[i][j], 0, 0, 0);
  }

  int mq = (lane >> 4) << 2;
#pragma unroll
  for (int i = 0; i < 4; ++i) {
#pragma unroll
    for (int j = 0; j < 4; ++j) {
      int n = wn + j * 16 + fm;
      float bsv = bias[n0 + n];
      f32x4 v = acc[i][j];
#pragma unroll
      for (int r = 0; r < 4; ++r) {
        float val = wgt * (v[r] + bsv);
        float* op = &obase[(size_t)(wm + i * 16 + mq + r) * HID + n];
        if (mode == 0) *op = val;
        else *op += val;
      }
    }
  }
}

// ---------------------------------------------------------------- launch
extern "C" void kernel_launch(void* const* d_in, const int* in_sizes, int n_in,
                              void* d_out, int out_size, void* d_ws, size_t ws_size,
                              hipStream_t stream) {
  (void)in_sizes; (void)n_in; (void)out_size;
  const float* x = (const float*)d_in[0];
  const int* sel = (const int*)d_in[1];
  const float* rw = (const float*)d_in[2];
  const float* wt[3] = {(const float*)d_in[3], (const float*)d_in[7], (const float*)d_in[11]};
  const float* bt[3] = {(const float*)d_in[4], (const float*)d_in[8], (const float*)d_in[12]};
  const float* wp[3] = {(const float*)d_in[5], (const float*)d_in[9], (const float*)d_in[13]};
  const float* bp[3] = {(const float*)d_in[6], (const float*)d_in[10], (const float*)d_in[14]};
  float* out = (float*)d_out;

  char* ws = (char*)d_ws;
  size_t off = 0;
  auto alloc = [&](size_t bytes) -> void* {
    off = (off + 255) & ~(size_t)255;
    void* p = ws + off;
    off += bytes;
    return p;
  };
  auto ceil128 = [](size_t m) -> size_t { return (m + 127) & ~(size_t)127; };

  float* w3 = (float*)alloc(64 * 3 * 4);
  int* koff0 = (int*)alloc(608 * 4);
  int* koff1 = (int*)alloc(608 * 4);
  int* koff2 = (int*)alloc(3072 * 4);
  int* ro0 = (int*)alloc((size_t)64 * 1024 * 4);
  int* ro1 = (int*)alloc((size_t)64 * 576 * 4);
  int* ro2 = (int*)alloc((size_t)64 * 196 * 4);
  int4* st1 = (int4*)alloc(1024 * 16);
  float4* wc1 = (float4*)alloc(1024 * 16);
  int4* st2 = (int4*)alloc(1024 * 16);
  float4* wc2 = (float4*)alloc(1024 * 16);
  unsigned short* wt0p = (unsigned short*)alloc((size_t)1024 * 608 * 2);
  unsigned short* wt1p = (unsigned short*)alloc((size_t)768 * 608 * 2);
  unsigned short* wt2p = (unsigned short*)alloc((size_t)1152 * 3072 * 2);
  unsigned short* wp0p = (unsigned short*)alloc((size_t)1024 * 1024 * 2);
  unsigned short* wp1p = (unsigned short*)alloc((size_t)1024 * 768 * 2);
  unsigned short* wp2p = (unsigned short*)alloc((size_t)1024 * 1152 * 2);
  const size_t NIMG = (size_t)64 * 3 * 448 * 448;  // 38,535,168
  unsigned short* xbf = (unsigned short*)alloc(NIMG * 2);
  size_t fixed_end = off;

  // per-chunk sizing: x336 img + tower feat + resized feat + im2col A
  auto ap_elems = [&](int bc) -> size_t {
    size_t a0 = (size_t)bc * 1024 * 608;
    size_t a1 = ceil128((size_t)bc * 576) * 608;
    size_t a2 = ceil128((size_t)bc * 196) * 3072;
    size_t m = a0 > a1 ? a0 : a1;
    return m > a2 ? m : a2;
  };
  auto need = [&](int bc) -> size_t {
    size_t el = (size_t)bc * 3 * 336 * 336 + (size_t)bc * 1024 * 1024 +
                (size_t)bc * 1024 * 1152 + ap_elems(bc);
    return el * 2 + 4 * 512;  // + alignment slack
  };
  int bch = 64;
  while (bch > 1 && fixed_end + need(bch) > ws_size) bch >>= 1;
  unsigned short* x336bf = (unsigned short*)alloc((size_t)bch * 3 * 336 * 336 * 2);
  unsigned short* Ftow = (unsigned short*)alloc((size_t)bch * 1024 * 1024 * 2);
  unsigned short* Fres = (unsigned short*)alloc((size_t)bch * 1024 * 1152 * 2);
  unsigned short* Apad = (unsigned short*)alloc(ap_elems(bch) * 2);

  // ---- prep
  k_weights<<<1, 64, 0, stream>>>(sel, rw, w3);
  k_img2bf<<<(int)((NIMG / 4 + 255) / 256), 256, 0, stream>>>(x, xbf, (int)(NIMG / 4));
  {
    int n0 = max(608, max(bch * 1024, 1024));
    int n1 = max(608, max(bch * 576, 1024));
    int n2 = max(3072, max(bch * 196, 1024));
    k_tables<<<(n0 + 255) / 256, 256, 0, stream>>>(koff0, ro0, st1, wc1, 448, 14, 32, 1024, bch, 588, 608);
    k_tables<<<(n1 + 255) / 256, 256, 0, stream>>>(koff1, ro1, st1, wc1, 336, 14, 24, 576, bch, 588, 608);
    k_tables<<<(n2 + 255) / 256, 256, 0, stream>>>(koff2, ro2, st2, wc2, 448, 32, 14, 196, bch, 3072, 3072);
  }
  k_pack_w<<<dim3(608 / 32, 1024 / 32), 256, 0, stream>>>(wt[0], wt0p, 588, 1024, 608);
  k_pack_w<<<dim3(608 / 32, 768 / 32), 256, 0, stream>>>(wt[1], wt1p, 588, 768, 608);
  k_pack_w<<<dim3(3072 / 32, 1152 / 32), 256, 0, stream>>>(wt[2], wt2p, 3072, 1152, 3072);
  k_pack_w<<<dim3(1024 / 32, 1024 / 32), 256, 0, stream>>>(wp[0], wp0p, 1024, 1024, 1024);
  k_pack_w<<<dim3(768 / 32, 1024 / 32), 256, 0, stream>>>(wp[1], wp1p, 768, 1024, 768);
  k_pack_w<<<dim3(1152 / 32, 1024 / 32), 256, 0, stream>>>(wp[2], wp2p, 1152, 1024, 1152);

  int nchunk = 64 / bch;
  for (int c = 0; c < nchunk; ++c) {
    int b0 = c * bch;
    const unsigned short* xc = xbf + (size_t)b0 * 3 * 448 * 448;
    dim3 gp(HID / 128, bch * 1024 / 128);

    // ---- Expert 0  (M always a multiple of 128: bch*1024)
    {
      int M = bch * 1024;
      int Mp = (int)ceil128((size_t)M);
      k_im2col<<<dim3(Mp, (608 / 2 + 255) / 256), 256, 0, stream>>>(xc, Apad, ro0, koff0, M, 588, 608);
      k_tower<<<dim3(1024 / 128, Mp / 128), 256, 0, stream>>>(Apad, wt0p, bt[0], Ftow, 1024, 608);
      k_proj<<<gp, 256, 0, stream>>>(Ftow, wp0p, bp[0], out, w3, b0, 0, 1024, 0);
    }
    // ---- Expert 1
    {
      int tot = bch * 3 * 336 * 336;
      k_resize_img<<<(tot + 255) / 256, 256, 0, stream>>>(x + (size_t)b0 * 3 * 448 * 448, x336bf, tot);
      int M = bch * 576;
      int Mp = (int)ceil128((size_t)M);
      k_im2col<<<dim3(Mp, (608 / 2 + 255) / 256), 256, 0, stream>>>(x336bf, Apad, ro1, koff1, M, 588, 608);
      k_tower<<<dim3(768 / 128, Mp / 128), 256, 0, stream>>>(Apad, wt1p, bt[1], Ftow, 768, 608);
      k_feat_resize<<<bch * 1024, 256, 0, stream>>>(Ftow, Fres, st1, wc1, 576, 768);
      k_proj<<<gp, 256, 0, stream>>>(Fres, wp1p, bp[1], out, w3, b0, 1, 768, 1);
    }
    // ---- Expert 2
    {
      int M = bch * 196;
      int Mp = (int)ceil128((size_t)M);
      k_im2col<<<dim3(Mp, (3072 / 2 + 255) / 256), 256, 0, stream>>>(xc, Apad, ro2, koff2, M, 3072, 3072);
      k_tower<<<dim3(1152 / 128, Mp / 128), 256, 0, stream>>>(Apad, wt2p, bt[2], Ftow, 1152, 3072);
      k_feat_resize<<<bch * 1024, 256, 0, stream>>>(Ftow, Fres, st2, wc2, 196, 1152);
      k_proj<<<gp, 256, 0, stream>>>(Fres, wp2p, bp[2], out, w3, b0, 2, 1152, 1);
    }
  }
}

// Round 2
// 1551.354 us; speedup vs baseline: 1.4962x; 1.2000x over previous
//
#include <hip/hip_runtime.h>
#include <cstddef>
#include <cstdint>

// VisionExperts on MI355X — bf16 MFMA, m97-style 128x128/BK=32 tiles.
//   E0: S=448 P=14 C=1024 G=32 T=1024 K=588->Kp608
//   E1: S=336 P=14 C=768  G=24 T=576  K=588->Kp608   (img 448->336, feat 24->32)
//   E2: S=448 P=32 C=1152 G=14 T=196  K=3072         (feat 14->32)
// Round-2 changes:
//  * k_proj3: ONE fused projector for all 3 experts (segmented-K GEMM,
//    per-expert register fold accT += w_e*acc_e) -> out written exactly once.
//    Replaces 3 k_proj launches that streamed 256MB fp32 out 3x (~940MB).
//  * XCD-chunked bijective blockIdx swizzle (T1/m204) on all big GEMMs:
//    consecutive same-A-panel blocks land on one XCD -> A fetched ~once.
//    (prev round: k_proj FETCH 534MB ~= 4x A matrix).
//  * im2col reads fp32 x directly (float2), xbf buffer + k_img2bf removed.

#define HID 1024

typedef __bf16 bf16x8 __attribute__((ext_vector_type(8)));
typedef float f32x4 __attribute__((ext_vector_type(4)));

__device__ __forceinline__ unsigned short f2bf(float f) {
  union { float f; unsigned u; } v; v.f = f;
  unsigned r = v.u + 0x7fffu + ((v.u >> 16) & 1u);  // RNE
  return (unsigned short)(r >> 16);
}
__device__ __forceinline__ float bf2f(unsigned h) {
  union { unsigned u; float f; } v; v.u = h << 16;
  return v.f;
}
__device__ __forceinline__ void gld16(const unsigned short* g, unsigned short* l) {
  auto gp = (const __attribute__((address_space(1))) unsigned int*)(const void*)g;
  auto lp = (__attribute__((address_space(3))) unsigned int*)(void*)l;
  __builtin_amdgcn_global_load_lds(gp, lp, 16, 0, 0);
}

// XCD-chunked bijective block swizzle (m204): block lin -> work id such that
// XCD c = lin%8 owns a contiguous chunk of the x-major work order.
__device__ __forceinline__ int2 swz128() {
  int gx = gridDim.x;
  int nwg = gx * gridDim.y;
  int lin = (int)(blockIdx.y * gx + blockIdx.x);
  int q = nwg >> 3, r = nwg & 7;
  int xcd = lin & 7, idx = lin >> 3;
  int wg = (xcd < r ? xcd * (q + 1) : r * (q + 1) + (xcd - r) * q) + idx;
  return make_int2((wg % gx) * 128, (wg / gx) * 128);
}

// ---------------------------------------------------------------- small prep kernels
__global__ void k_weights(const int* __restrict__ sel, const float* __restrict__ rw,
                          float* __restrict__ w3) {
  int b = threadIdx.x;
  if (b < 64) {
    float w0 = 0.f, w1 = 0.f, w2 = 0.f;
    for (int k = 0; k < 2; ++k) {
      int e = sel[b * 2 + k];
      float r = rw[b * 2 + k];
      if (e == 0) w0 += r; else if (e == 1) w1 += r; else w2 += r;
    }
    w3[b * 3 + 0] = w0; w3[b * 3 + 1] = w1; w3[b * 3 + 2] = w2;
  }
}

// combined projector bias per sample: cb[s][n] = sum_e w3[s][e]*bp_e[n]
__global__ void k_cbias(const float* __restrict__ w3, const float* __restrict__ b0,
                        const float* __restrict__ b1, const float* __restrict__ b2,
                        float* __restrict__ cb) {
  int s = blockIdx.x;
  float w0 = w3[s * 3], w1 = w3[s * 3 + 1], w2 = w3[s * 3 + 2];
  for (int n = threadIdx.x; n < HID; n += 256)
    cb[s * HID + n] = w0 * b0[n] + w1 * b1[n] + w2 * b2[n];
}

__global__ void k_tables(int* __restrict__ koff, int* __restrict__ rowoff,
                         int4* __restrict__ stok, float4* __restrict__ wco,
                         int S, int P, int G, int T, int bch, int K, int Kp) {
  int idx = blockIdx.x * 256 + threadIdx.x;
  if (idx < Kp) {
    if (idx < K) {
      int pp = P * P;
      int ch = idx / pp;
      int r = idx - ch * pp;
      int py = r / P;
      int px = r - py * P;
      koff[idx] = ch * S * S + py * S + px;
    } else koff[idx] = 0;
  }
  int nro = bch * T;
  if (idx < nro) {
    int bl = idx / T;
    int t = idx - bl * T;
    int gy = t / G;
    int gx = t - gy * G;
    rowoff[idx] = bl * 3 * S * S + gy * P * S + gx * P;
  }
  if (idx < 1024) {
    int oy = idx >> 5, ox = idx & 31;
    float sc = (float)(G - 1) / 31.0f;
    float fy = oy * sc, fx = ox * sc;
    int y0 = (int)floorf(fy), x0 = (int)floorf(fx);
    float ty = fy - y0, tx = fx - x0;
    int y1 = min(y0 + 1, G - 1), x1 = min(x0 + 1, G - 1);
    stok[idx] = make_int4(y0 * G + x0, y0 * G + x1, y1 * G + x0, y1 * G + x1);
    wco[idx] = make_float4((1.f - ty) * (1.f - tx), (1.f - ty) * tx,
                           ty * (1.f - tx), ty * tx);
  }
}

__global__ void k_resize_img(const float* __restrict__ x, unsigned short* __restrict__ o,
                             int total) {
  int idx = blockIdx.x * 256 + threadIdx.x;
  if (idx >= total) return;
  int ox = idx % 336;
  int t = idx / 336;
  int oy = t % 336;
  int bc = t / 336;
  const float sc = 447.0f / 335.0f;
  float fy = oy * sc, fx = ox * sc;
  int y0 = (int)floorf(fy), x0 = (int)floorf(fx);
  float ty = fy - y0, tx = fx - x0;
  int y1 = min(y0 + 1, 447), x1 = min(x0 + 1, 447);
  const float* p = x + (size_t)bc * 448 * 448;
  float v00 = p[y0 * 448 + x0], v01 = p[y0 * 448 + x1];
  float v10 = p[y1 * 448 + x0], v11 = p[y1 * 448 + x1];
  float r0 = v00 * (1.f - ty) + v10 * ty;
  float r1 = v01 * (1.f - ty) + v11 * ty;
  o[idx] = f2bf(r0 * (1.f - tx) + r1 * tx);
}

// W [K][N] fp32 -> Wp [N][Kp] bf16 (zero-pad K..Kp), 32x32 LDS tile transpose
__global__ void k_pack_w(const float* __restrict__ W, unsigned short* __restrict__ Wp,
                         int K, int N, int Kp) {
  __shared__ float t[32][33];
  int kb = blockIdx.x * 32, nb = blockIdx.y * 32;
  int tx = threadIdx.x & 31, ty = threadIdx.x >> 5;
#pragma unroll
  for (int r = 0; r < 32; r += 8) {
    int k = kb + ty + r, n = nb + tx;
    t[ty + r][tx] = (k < K) ? W[(size_t)k * N + n] : 0.f;
  }
  __syncthreads();
#pragma unroll
  for (int r = 0; r < 32; r += 8) {
    int n = nb + ty + r, k = kb + tx;
    if (k < Kp) Wp[(size_t)n * Kp + k] = f2bf(t[tx][ty + r]);
  }
}

// ---------------------------------------------------------------- im2col
// Ap[m][k] = cvt(img[rowoff[m] + koff[k]]) for m<M,k<K; zero elsewhere.
// x2 along k: patch-row runs start at even k AND even pixel offset, so pairs
// (k,k+1) with even k map to aligned contiguous pixel pairs.
__global__ void k_im2col_f32(const float* __restrict__ img, unsigned short* __restrict__ Ap,
                             const int* __restrict__ rowoff, const int* __restrict__ koff,
                             int M, int K, int Kp) {
  int k2 = (blockIdx.y * 256 + threadIdx.x) * 2;
  if (k2 >= Kp) return;
  int m = blockIdx.x;
  unsigned v = 0;
  if (m < M && k2 < K) {
    float2 f = *(const float2*)(const void*)&img[rowoff[m] + koff[k2]];
    v = (unsigned)f2bf(f.x) | ((unsigned)f2bf(f.y) << 16);
  }
  *(unsigned*)(void*)&Ap[(size_t)m * Kp + k2] = v;
}

__global__ void k_im2col_bf16(const unsigned short* __restrict__ img,
                              unsigned short* __restrict__ Ap,
                              const int* __restrict__ rowoff, const int* __restrict__ koff,
                              int M, int K, int Kp) {
  int k2 = (blockIdx.y * 256 + threadIdx.x) * 2;
  if (k2 >= Kp) return;
  int m = blockIdx.x;
  unsigned v = 0;
  if (m < M && k2 < K)
    v = *(const unsigned*)(const void*)&img[rowoff[m] + koff[k2]];
  *(unsigned*)(void*)&Ap[(size_t)m * Kp + k2] = v;
}

// ---------------------------------------------------------------- tower GEMM (bf16 MFMA)
// Fp[m][n] = bf16( sum_k Ap[m][k]*Wp[n][k] + bias[n] ); rows [M,Mp) zero-padded.
__global__ __launch_bounds__(256) void k_tower(
    const unsigned short* __restrict__ Ap, const unsigned short* __restrict__ Wp,
    const float* __restrict__ bias, unsigned short* __restrict__ Fp,
    int N, int Kp) {
  __shared__ __align__(16) unsigned short As[128 * 32];
  __shared__ __align__(16) unsigned short Bs[128 * 32];
  int tid = threadIdx.x, wave = tid >> 6, lane = tid & 63;
  int2 sw = swz128();
  int n0 = sw.x, m0 = sw.y;

  const unsigned short* arow0 = Ap + (size_t)(m0 + (tid >> 2)) * Kp + (tid & 3) * 8;
  const unsigned short* arow1 = arow0 + (size_t)64 * Kp;
  const unsigned short* wrow0 = Wp + (size_t)(n0 + (tid >> 2)) * Kp + (tid & 3) * 8;
  const unsigned short* wrow1 = wrow0 + (size_t)64 * Kp;
  unsigned short* AsW0 = As + wave * 512;
  unsigned short* AsW1 = As + 2048 + wave * 512;
  unsigned short* BsW0 = Bs + wave * 512;
  unsigned short* BsW1 = Bs + 2048 + wave * 512;

  int wm = (wave >> 1) << 6, wn = (wave & 1) << 6;
  int fm = lane & 15, fq = (lane >> 4) << 3;
  f32x4 acc[4][4] = {};

  for (int kb = 0; kb < Kp; kb += 32) {
    __syncthreads();
    gld16(arow0 + kb, AsW0);
    gld16(arow1 + kb, AsW1);
    gld16(wrow0 + kb, BsW0);
    gld16(wrow1 + kb, BsW1);
    __syncthreads();
    bf16x8 af[4], bfr[4];
#pragma unroll
    for (int i = 0; i < 4; ++i) af[i] = *(const bf16x8*)&As[(wm + i * 16 + fm) * 32 + fq];
#pragma unroll
    for (int j = 0; j < 4; ++j) bfr[j] = *(const bf16x8*)&Bs[(wn + j * 16 + fm) * 32 + fq];
#pragma unroll
    for (int i = 0; i < 4; ++i)
#pragma unroll
      for (int j = 0; j < 4; ++j)
        acc[i][j] = __builtin_amdgcn_mfma_f32_16x16x32_bf16(af[i], bfr[j], acc[i][j], 0, 0, 0);
  }

  int mq = (lane >> 4) << 2;
#pragma unroll
  for (int i = 0; i < 4; ++i) {
    int mbase = m0 + wm + i * 16 + mq;
#pragma unroll
    for (int j = 0; j < 4; ++j) {
      int n = n0 + wn + j * 16 + fm;
      float bsv = bias[n];
      f32x4 v = acc[i][j];
#pragma unroll
      for (int r = 0; r < 4; ++r)
        Fp[(size_t)(mbase + r) * N + n] = f2bf(v[r] + bsv);
    }
  }
}

// ---------------------------------------------------------------- feature-grid resize (bf16)
__global__ void k_feat_resize(const unsigned short* __restrict__ C1,
                              unsigned short* __restrict__ F,
                              const int4* __restrict__ stok, const float4* __restrict__ wco,
                              int Tsrc, int C) {
  int bt = blockIdx.x;
  int bl = bt >> 10, t = bt & 1023;
  int4 s = stok[t];
  float4 w = wco[t];
  const unsigned* b32 = (const unsigned*)(C1 + (size_t)bl * Tsrc * C);
  unsigned* o32 = (unsigned*)(F + (size_t)bt * C);
  int C2 = C >> 1;
  int r0 = s.x * C2, r1 = s.y * C2, r2 = s.z * C2, r3 = s.w * C2;
  for (int c = threadIdx.x; c < C2; c += 256) {
    unsigned p0 = b32[r0 + c], p1 = b32[r1 + c], p2 = b32[r2 + c], p3 = b32[r3 + c];
    float lo = w.x * bf2f(p0 & 0xffffu) + w.y * bf2f(p1 & 0xffffu) +
               w.z * bf2f(p2 & 0xffffu) + w.w * bf2f(p3 & 0xffffu);
    float hi = w.x * bf2f(p0 >> 16) + w.y * bf2f(p1 >> 16) +
               w.z * bf2f(p2 >> 16) + w.w * bf2f(p3 >> 16);
    o32[c] = (unsigned)f2bf(lo) | ((unsigned)f2bf(hi) << 16);
  }
}

// ---------------------------------------------------------------- fused projector GEMM
// out[m][n] = sum_e w_e(sample(m)) * (A_e[m] @ W_e[:,n]) + cb[sample(m)][n]
// Segmented-K: per active expert run its K-loop into acc, fold accT += w*acc.
__global__ __launch_bounds__(256) void k_proj3(
    const unsigned short* __restrict__ A0, const unsigned short* __restrict__ A1,
    const unsigned short* __restrict__ A2,
    const unsigned short* __restrict__ W0, const unsigned short* __restrict__ W1,
    const unsigned short* __restrict__ W2,
    const float* __restrict__ cb, float* __restrict__ out,
    const float* __restrict__ w3, int b0) {
  __shared__ __align__(16) unsigned short As[128 * 32];
  __shared__ __align__(16) unsigned short Bs[128 * 32];
  int tid = threadIdx.x, wave = tid >> 6, lane = tid & 63;
  int2 sw = swz128();
  int n0 = sw.x, m0 = sw.y;
  int s = b0 + (m0 >> 10);
  float wg0 = w3[s * 3], wg1 = w3[s * 3 + 1], wg2 = w3[s * 3 + 2];
  const float wgs[3] = {wg0, wg1, wg2};
  const unsigned short* Ae[3] = {A0, A1, A2};
  const unsigned short* We[3] = {W0, W1, W2};
  const int Ke[3] = {1024, 768, 1152};

  unsigned short* AsW0 = As + wave * 512;
  unsigned short* AsW1 = As + 2048 + wave * 512;
  unsigned short* BsW0 = Bs + wave * 512;
  unsigned short* BsW1 = Bs + 2048 + wave * 512;
  int wm = (wave >> 1) << 6, wn = (wave & 1) << 6;
  int fm = lane & 15, fq = (lane >> 4) << 3;

  f32x4 accT[4][4] = {};

#pragma unroll
  for (int e = 0; e < 3; ++e) {
    float w = wgs[e];
    if (w == 0.f) continue;
    int K = Ke[e];
    const unsigned short* arow0 = Ae[e] + (size_t)(m0 + (tid >> 2)) * K + (tid & 3) * 8;
    const unsigned short* arow1 = arow0 + (size_t)64 * K;
    const unsigned short* wrow0 = We[e] + (size_t)(n0 + (tid >> 2)) * K + (tid & 3) * 8;
    const unsigned short* wrow1 = wrow0 + (size_t)64 * K;
    f32x4 acc[4][4] = {};
    for (int kb = 0; kb < K; kb += 32) {
      __syncthreads();
      gld16(arow0 + kb, AsW0);
      gld16(arow1 + kb, AsW1);
      gld16(wrow0 + kb, BsW0);
      gld16(wrow1 + kb, BsW1);
      __syncthreads();
      bf16x8 af[4], bfr[4];
#pragma unroll
      for (int i = 0; i < 4; ++i) af[i] = *(const bf16x8*)&As[(wm + i * 16 + fm) * 32 + fq];
#pragma unroll
      for (int j = 0; j < 4; ++j) bfr[j] = *(const bf16x8*)&Bs[(wn + j * 16 + fm) * 32 + fq];
#pragma unroll
      for (int i = 0; i < 4; ++i)
#pragma unroll
        for (int j = 0; j < 4; ++j)
          acc[i][j] = __builtin_amdgcn_mfma_f32_16x16x32_bf16(af[i], bfr[j], acc[i][j], 0, 0, 0);
    }
#pragma unroll
    for (int i = 0; i < 4; ++i)
#pragma unroll
      for (int j = 0; j < 4; ++j)
        accT[i][j] += w * acc[i][j];
  }

  int mq = (lane >> 4) << 2;
  float* obase = out + ((size_t)b0 * 1024 + (size_t)m0) * HID + n0;
  const float* cbs = cb + (size_t)s * HID + n0;
#pragma unroll
  for (int i = 0; i < 4; ++i) {
#pragma unroll
    for (int j = 0; j < 4; ++j) {
      int n = wn + j * 16 + fm;
      float cbv = cbs[n];
      f32x4 v = accT[i][j];
#pragma unroll
      for (int r = 0; r < 4; ++r)
        obase[(size_t)(wm + i * 16 + mq + r) * HID + n] = v[r] + cbv;
    }
  }
}

// ---------------------------------------------------------------- launch
extern "C" void kernel_launch(void* const* d_in, const int* in_sizes, int n_in,
                              void* d_out, int out_size, void* d_ws, size_t ws_size,
                              hipStream_t stream) {
  (void)in_sizes; (void)n_in; (void)out_size;
  const float* x = (const float*)d_in[0];
  const int* sel = (const int*)d_in[1];
  const float* rw = (const float*)d_in[2];
  const float* wt[3] = {(const float*)d_in[3], (const float*)d_in[7], (const float*)d_in[11]};
  const float* bt[3] = {(const float*)d_in[4], (const float*)d_in[8], (const float*)d_in[12]};
  const float* wp[3] = {(const float*)d_in[5], (const float*)d_in[9], (const float*)d_in[13]};
  const float* bp[3] = {(const float*)d_in[6], (const float*)d_in[10], (const float*)d_in[14]};
  float* out = (float*)d_out;

  char* ws = (char*)d_ws;
  size_t off = 0;
  auto alloc = [&](size_t bytes) -> void* {
    off = (off + 255) & ~(size_t)255;
    void* p = ws + off;
    off += bytes;
    return p;
  };
  auto ceil128 = [](size_t m) -> size_t { return (m + 127) & ~(size_t)127; };

  float* w3 = (float*)alloc(64 * 3 * 4);
  float* cb = (float*)alloc((size_t)64 * HID * 4);
  int* koff0 = (int*)alloc(608 * 4);
  int* koff1 = (int*)alloc(608 * 4);
  int* koff2 = (int*)alloc(3072 * 4);
  int* ro0 = (int*)alloc((size_t)64 * 1024 * 4);
  int* ro1 = (int*)alloc((size_t)64 * 576 * 4);
  int* ro2 = (int*)alloc((size_t)64 * 196 * 4);
  int4* st1 = (int4*)alloc(1024 * 16);
  float4* wc1 = (float4*)alloc(1024 * 16);
  int4* st2 = (int4*)alloc(1024 * 16);
  float4* wc2 = (float4*)alloc(1024 * 16);
  unsigned short* wt0p = (unsigned short*)alloc((size_t)1024 * 608 * 2);
  unsigned short* wt1p = (unsigned short*)alloc((size_t)768 * 608 * 2);
  unsigned short* wt2p = (unsigned short*)alloc((size_t)1152 * 3072 * 2);
  unsigned short* wp0p = (unsigned short*)alloc((size_t)1024 * 1024 * 2);
  unsigned short* wp1p = (unsigned short*)alloc((size_t)1024 * 768 * 2);
  unsigned short* wp2p = (unsigned short*)alloc((size_t)1024 * 1152 * 2);
  size_t fixed_end = off;

  // chunk buffers: F0/F1/F2 feature mats (live until k_proj3) + overlapped scratch
  auto scratch_elems = [&](int bc) -> size_t {
    size_t a0 = (size_t)bc * 1024 * 608;                                    // E0 Apad
    size_t a1 = (size_t)bc * 3 * 336 * 336 + ceil128((size_t)bc * 576) * 608;  // x336 + E1 Apad
    size_t a2 = ceil128((size_t)bc * 196) * (3072 + 1152);                  // E2 Apad + Ftow2
    size_t m = a0 > a1 ? a0 : a1;
    return m > a2 ? m : a2;
  };
  auto need = [&](int bc) -> size_t {
    size_t el = (size_t)bc * 1024 * (1024 + 768 + 1152) + scratch_elems(bc);
    return el * 2 + 16 * 512;
  };
  int bch = 64;
  while (bch > 1 && fixed_end + need(bch) > ws_size) bch >>= 1;
  unsigned short* F0 = (unsigned short*)alloc((size_t)bch * 1024 * 1024 * 2);
  unsigned short* F1 = (unsigned short*)alloc((size_t)bch * 1024 * 768 * 2);
  unsigned short* F2 = (unsigned short*)alloc((size_t)bch * 1024 * 1152 * 2);
  unsigned short* scratch = (unsigned short*)alloc(scratch_elems(bch) * 2);

  int M1 = bch * 576, Mp1 = (int)ceil128((size_t)M1);
  int M2 = bch * 196, Mp2 = (int)ceil128((size_t)M2);
  unsigned short* x336 = scratch;                                   // phase E1
  unsigned short* Apad1 = scratch + (size_t)bch * 3 * 336 * 336;    // phase E1
  unsigned short* Apad2 = scratch;                                  // phase E2
  unsigned short* Ftow2 = scratch + (size_t)Mp2 * 3072;             // phase E2
  unsigned short* Ftow1 = F2;  // E1 tower tmp lives in F2 region (F2 written later)

  // ---- prep
  k_weights<<<1, 64, 0, stream>>>(sel, rw, w3);
  k_cbias<<<64, 256, 0, stream>>>(w3, bp[0], bp[1], bp[2], cb);
  {
    int n0 = max(608, max(bch * 1024, 1024));
    int n1 = max(608, max(bch * 576, 1024));
    int n2 = max(3072, max(bch * 196, 1024));
    k_tables<<<(n0 + 255) / 256, 256, 0, stream>>>(koff0, ro0, st1, wc1, 448, 14, 32, 1024, bch, 588, 608);
    k_tables<<<(n1 + 255) / 256, 256, 0, stream>>>(koff1, ro1, st1, wc1, 336, 14, 24, 576, bch, 588, 608);
    k_tables<<<(n2 + 255) / 256, 256, 0, stream>>>(koff2, ro2, st2, wc2, 448, 32, 14, 196, bch, 3072, 3072);
  }
  k_pack_w<<<dim3(608 / 32, 1024 / 32), 256, 0, stream>>>(wt[0], wt0p, 588, 1024, 608);
  k_pack_w<<<dim3(608 / 32, 768 / 32), 256, 0, stream>>>(wt[1], wt1p, 588, 768, 608);
  k_pack_w<<<dim3(3072 / 32, 1152 / 32), 256, 0, stream>>>(wt[2], wt2p, 3072, 1152, 3072);
  k_pack_w<<<dim3(1024 / 32, 1024 / 32), 256, 0, stream>>>(wp[0], wp0p, 1024, 1024, 1024);
  k_pack_w<<<dim3(768 / 32, 1024 / 32), 256, 0, stream>>>(wp[1], wp1p, 768, 1024, 768);
  k_pack_w<<<dim3(1152 / 32, 1024 / 32), 256, 0, stream>>>(wp[2], wp2p, 1152, 1024, 1152);

  int nchunk = 64 / bch;
  for (int c = 0; c < nchunk; ++c) {
    int b0 = c * bch;
    const float* xc = x + (size_t)b0 * 3 * 448 * 448;

    // ---- Expert 0 tower  (M = bch*1024, always /128)
    {
      int M = bch * 1024;
      k_im2col_f32<<<dim3(M, 2), 256, 0, stream>>>(xc, scratch, ro0, koff0, M, 588, 608);
      k_tower<<<dim3(1024 / 128, M / 128), 256, 0, stream>>>(scratch, wt0p, bt[0], F0, 1024, 608);
    }
    // ---- Expert 1 tower + feat resize
    {
      int tot = bch * 3 * 336 * 336;
      k_resize_img<<<(tot + 255) / 256, 256, 0, stream>>>(xc, x336, tot);
      k_im2col_bf16<<<dim3(Mp1, 2), 256, 0, stream>>>(x336, Apad1, ro1, koff1, M1, 588, 608);
      k_tower<<<dim3(768 / 128, Mp1 / 128), 256, 0, stream>>>(Apad1, wt1p, bt[1], Ftow1, 768, 608);
      k_feat_resize<<<bch * 1024, 256, 0, stream>>>(Ftow1, F1, st1, wc1, 576, 768);
    }
    // ---- Expert 2 tower + feat resize
    {
      k_im2col_f32<<<dim3(Mp2, 6), 256, 0, stream>>>(xc, Apad2, ro2, koff2, M2, 3072, 3072);
      k_tower<<<dim3(1152 / 128, Mp2 / 128), 256, 0, stream>>>(Apad2, wt2p, bt[2], Ftow2, 1152, 3072);
      k_feat_resize<<<bch * 1024, 256, 0, stream>>>(Ftow2, F2, st2, wc2, 196, 1152);
    }
    // ---- fused projector (out written exactly once)
    k_proj3<<<dim3(HID / 128, bch * 1024 / 128), 256, 0, stream>>>(
        F0, F1, F2, wp0p, wp1p, wp2p, cb, out, w3, b0);
  }
}

// Round 3
// 1369.616 us; speedup vs baseline: 1.6948x; 1.1327x over previous
//
#include <hip/hip_runtime.h>
#include <cstddef>
#include <cstdint>

// VisionExperts on MI355X — bf16 MFMA, m97-style 128x128/BK=32 tiles.
//   E0: S=448 P=14 C=1024 G=32 T=1024 K=588->Kp608
//   E1: S=336 P=14 C=768  G=24 T=576  K=588->Kp608   (img 448->336)
//   E2: S=448 P=32 C=1152 G=14 T=196  K=3072
// Round-3 changes:
//  * Resize<->project commuted (both linear): project tower features at T_src
//    (576/196 tokens), THEN bilinear-interp the f32 projected panels.
//    Kills k_feat_resize + 250MB F1/F2 round-trip; E1 proj FLOPs -45%, E2 -5x.
//    Bias commutes (interp weights sum to 1) -> stays folded in cb.
//  * proj0 writes out = w0*acc + cb directly (E0 needs no interp);
//    k_combine streams out += w1*interp(P1) + w2*interp(P2) (RMW once).
//  * Early-exit for inactive (w_e==0) samples in im2col/resize/towers/projs:
//    GEMM rows are independent, unread garbage rows are safe. ~1/3 of E0/E1
//    tower+proj work skipped.

#define HID 1024

typedef __bf16 bf16x8 __attribute__((ext_vector_type(8)));
typedef float f32x4 __attribute__((ext_vector_type(4)));

__device__ __forceinline__ unsigned short f2bf(float f) {
  union { float f; unsigned u; } v; v.f = f;
  unsigned r = v.u + 0x7fffu + ((v.u >> 16) & 1u);  // RNE
  return (unsigned short)(r >> 16);
}
__device__ __forceinline__ float bf2f(unsigned h) {
  union { unsigned u; float f; } v; v.u = h << 16;
  return v.f;
}
__device__ __forceinline__ void gld16(const unsigned short* g, unsigned short* l) {
  auto gp = (const __attribute__((address_space(1))) unsigned int*)(const void*)g;
  auto lp = (__attribute__((address_space(3))) unsigned int*)(void*)l;
  __builtin_amdgcn_global_load_lds(gp, lp, 16, 0, 0);
}

// XCD-chunked bijective block swizzle (m204): XCD c = lin%8 owns a contiguous
// chunk of the x-major work order.
__device__ __forceinline__ int2 swz128() {
  int gx = gridDim.x;
  int nwg = gx * gridDim.y;
  int lin = (int)(blockIdx.y * gx + blockIdx.x);
  int q = nwg >> 3, r = nwg & 7;
  int xcd = lin & 7, idx = lin >> 3;
  int wg = (xcd < r ? xcd * (q + 1) : r * (q + 1) + (xcd - r) * q) + idx;
  return make_int2((wg % gx) * 128, (wg / gx) * 128);
}

// ---------------------------------------------------------------- small prep kernels
__global__ void k_weights(const int* __restrict__ sel, const float* __restrict__ rw,
                          float* __restrict__ w3) {
  int b = threadIdx.x;
  if (b < 64) {
    float w0 = 0.f, w1 = 0.f, w2 = 0.f;
    for (int k = 0; k < 2; ++k) {
      int e = sel[b * 2 + k];
      float r = rw[b * 2 + k];
      if (e == 0) w0 += r; else if (e == 1) w1 += r; else w2 += r;
    }
    w3[b * 3 + 0] = w0; w3[b * 3 + 1] = w1; w3[b * 3 + 2] = w2;
  }
}

// combined projector bias per sample: cb[s][n] = sum_e w3[s][e]*bp_e[n]
__global__ void k_cbias(const float* __restrict__ w3, const float* __restrict__ b0,
                        const float* __restrict__ b1, const float* __restrict__ b2,
                        float* __restrict__ cb) {
  int s = blockIdx.x;
  float w0 = w3[s * 3], w1 = w3[s * 3 + 1], w2 = w3[s * 3 + 2];
  for (int n = threadIdx.x; n < HID; n += 256)
    cb[s * HID + n] = w0 * b0[n] + w1 * b1[n] + w2 * b2[n];
}

__global__ void k_tables(int* __restrict__ koff, int* __restrict__ rowoff,
                         int4* __restrict__ stok, float4* __restrict__ wco,
                         int S, int P, int G, int T, int bch, int K, int Kp) {
  int idx = blockIdx.x * 256 + threadIdx.x;
  if (idx < Kp) {
    if (idx < K) {
      int pp = P * P;
      int ch = idx / pp;
      int r = idx - ch * pp;
      int py = r / P;
      int px = r - py * P;
      koff[idx] = ch * S * S + py * S + px;
    } else koff[idx] = 0;
  }
  int nro = bch * T;
  if (idx < nro) {
    int bl = idx / T;
    int t = idx - bl * T;
    int gy = t / G;
    int gx = t - gy * G;
    rowoff[idx] = bl * 3 * S * S + gy * P * S + gx * P;
  }
  if (idx < 1024) {
    int oy = idx >> 5, ox = idx & 31;
    float sc = (float)(G - 1) / 31.0f;
    float fy = oy * sc, fx = ox * sc;
    int y0 = (int)floorf(fy), x0 = (int)floorf(fx);
    float ty = fy - y0, tx = fx - x0;
    int y1 = min(y0 + 1, G - 1), x1 = min(x0 + 1, G - 1);
    stok[idx] = make_int4(y0 * G + x0, y0 * G + x1, y1 * G + x0, y1 * G + x1);
    wco[idx] = make_float4((1.f - ty) * (1.f - tx), (1.f - ty) * tx,
                           ty * (1.f - tx), ty * tx);
  }
}

__global__ void k_resize_img(const float* __restrict__ x, unsigned short* __restrict__ o,
                             int total, const float* __restrict__ w3, int b0) {
  int idx = blockIdx.x * 256 + threadIdx.x;
  if (idx >= total) return;
  int bc = idx / (336 * 336);
  if (w3[(b0 + bc / 3) * 3 + 1] == 0.f) return;  // E1 inactive sample
  int ox = idx % 336;
  int oy = (idx / 336) % 336;
  const float sc = 447.0f / 335.0f;
  float fy = oy * sc, fx = ox * sc;
  int y0 = (int)floorf(fy), x0 = (int)floorf(fx);
  float ty = fy - y0, tx = fx - x0;
  int y1 = min(y0 + 1, 447), x1 = min(x0 + 1, 447);
  const float* p = x + (size_t)bc * 448 * 448;
  float v00 = p[y0 * 448 + x0], v01 = p[y0 * 448 + x1];
  float v10 = p[y1 * 448 + x0], v11 = p[y1 * 448 + x1];
  float r0 = v00 * (1.f - ty) + v10 * ty;
  float r1 = v01 * (1.f - ty) + v11 * ty;
  o[idx] = f2bf(r0 * (1.f - tx) + r1 * tx);
}

// W [K][N] fp32 -> Wp [N][Kp] bf16 (zero-pad K..Kp), 32x32 LDS tile transpose
__global__ void k_pack_w(const float* __restrict__ W, unsigned short* __restrict__ Wp,
                         int K, int N, int Kp) {
  __shared__ float t[32][33];
  int kb = blockIdx.x * 32, nb = blockIdx.y * 32;
  int tx = threadIdx.x & 31, ty = threadIdx.x >> 5;
#pragma unroll
  for (int r = 0; r < 32; r += 8) {
    int k = kb + ty + r, n = nb + tx;
    t[ty + r][tx] = (k < K) ? W[(size_t)k * N + n] : 0.f;
  }
  __syncthreads();
#pragma unroll
  for (int r = 0; r < 32; r += 8) {
    int n = nb + ty + r, k = kb + tx;
    if (k < Kp) Wp[(size_t)n * Kp + k] = f2bf(t[tx][ty + r]);
  }
}

// ---------------------------------------------------------------- im2col
// Ap[m][k] = cvt(img[rowoff[m]+koff[k]]) for m<M,k<K; k-padding zeroed.
// Skips rows of inactive samples (rows never read downstream).
__global__ void k_im2col_f32(const float* __restrict__ img, unsigned short* __restrict__ Ap,
                             const int* __restrict__ rowoff, const int* __restrict__ koff,
                             int M, int K, int Kp,
                             const float* __restrict__ w3, int b0, int e, int T) {
  int m = blockIdx.x;
  if (m >= M) return;
  if (w3[(b0 + m / T) * 3 + e] == 0.f) return;
  int k2 = (blockIdx.y * 256 + threadIdx.x) * 2;
  if (k2 >= Kp) return;
  unsigned v = 0;
  if (k2 < K) {
    float2 f = *(const float2*)(const void*)&img[rowoff[m] + koff[k2]];
    v = (unsigned)f2bf(f.x) | ((unsigned)f2bf(f.y) << 16);
  }
  *(unsigned*)(void*)&Ap[(size_t)m * Kp + k2] = v;
}

__global__ void k_im2col_bf16(const unsigned short* __restrict__ img,
                              unsigned short* __restrict__ Ap,
                              const int* __restrict__ rowoff, const int* __restrict__ koff,
                              int M, int K, int Kp,
                              const float* __restrict__ w3, int b0, int e, int T) {
  int m = blockIdx.x;
  if (m >= M) return;
  if (w3[(b0 + m / T) * 3 + e] == 0.f) return;
  int k2 = (blockIdx.y * 256 + threadIdx.x) * 2;
  if (k2 >= Kp) return;
  unsigned v = 0;
  if (k2 < K)
    v = *(const unsigned*)(const void*)&img[rowoff[m] + koff[k2]];
  *(unsigned*)(void*)&Ap[(size_t)m * Kp + k2] = v;
}

// ---------------------------------------------------------------- tower GEMM (bf16 MFMA)
// Fp[m][n] = bf16( sum_k Ap[m][k]*Wp[n][k] + bias[n] ).
// Tile skipped if all covered samples inactive for expert e.
__global__ __launch_bounds__(256) void k_tower(
    const unsigned short* __restrict__ Ap, const unsigned short* __restrict__ Wp,
    const float* __restrict__ bias, unsigned short* __restrict__ Fp,
    int N, int Kp, const float* __restrict__ w3, int b0, int e, int T, int bch) {
  __shared__ __align__(16) unsigned short As[128 * 32];
  __shared__ __align__(16) unsigned short Bs[128 * 32];
  int tid = threadIdx.x, wave = tid >> 6, lane = tid & 63;
  int2 sw = swz128();
  int n0 = sw.x, m0 = sw.y;

  {
    int s0 = m0 / T, s1 = (m0 + 127) / T;
    if (s1 >= bch) s1 = bch - 1;
    bool act = false;
    for (int s = s0; s <= s1; ++s) act |= (w3[(b0 + s) * 3 + e] != 0.f);
    if (!act) return;
  }

  const unsigned short* arow0 = Ap + (size_t)(m0 + (tid >> 2)) * Kp + (tid & 3) * 8;
  const unsigned short* arow1 = arow0 + (size_t)64 * Kp;
  const unsigned short* wrow0 = Wp + (size_t)(n0 + (tid >> 2)) * Kp + (tid & 3) * 8;
  const unsigned short* wrow1 = wrow0 + (size_t)64 * Kp;
  unsigned short* AsW0 = As + wave * 512;
  unsigned short* AsW1 = As + 2048 + wave * 512;
  unsigned short* BsW0 = Bs + wave * 512;
  unsigned short* BsW1 = Bs + 2048 + wave * 512;

  int wm = (wave >> 1) << 6, wn = (wave & 1) << 6;
  int fm = lane & 15, fq = (lane >> 4) << 3;
  f32x4 acc[4][4] = {};

  for (int kb = 0; kb < Kp; kb += 32) {
    __syncthreads();
    gld16(arow0 + kb, AsW0);
    gld16(arow1 + kb, AsW1);
    gld16(wrow0 + kb, BsW0);
    gld16(wrow1 + kb, BsW1);
    __syncthreads();
    bf16x8 af[4], bfr[4];
#pragma unroll
    for (int i = 0; i < 4; ++i) af[i] = *(const bf16x8*)&As[(wm + i * 16 + fm) * 32 + fq];
#pragma unroll
    for (int j = 0; j < 4; ++j) bfr[j] = *(const bf16x8*)&Bs[(wn + j * 16 + fm) * 32 + fq];
#pragma unroll
    for (int i = 0; i < 4; ++i)
#pragma unroll
      for (int j = 0; j < 4; ++j)
        acc[i][j] = __builtin_amdgcn_mfma_f32_16x16x32_bf16(af[i], bfr[j], acc[i][j], 0, 0, 0);
  }

  int mq = (lane >> 4) << 2;
#pragma unroll
  for (int i = 0; i < 4; ++i) {
    int mbase = m0 + wm + i * 16 + mq;
#pragma unroll
    for (int j = 0; j < 4; ++j) {
      int n = n0 + wn + j * 16 + fm;
      float bsv = bias[n];
      f32x4 v = acc[i][j];
#pragma unroll
      for (int r = 0; r < 4; ++r)
        Fp[(size_t)(mbase + r) * N + n] = f2bf(v[r] + bsv);
    }
  }
}

// ---------------------------------------------------------------- projector GEMMs
// proj0: out = w0*(F0 @ W0) + cb  (E0 is identity-resize; writes out base once)
__global__ __launch_bounds__(256) void k_proj0(
    const unsigned short* __restrict__ A, const unsigned short* __restrict__ W,
    const float* __restrict__ cb, float* __restrict__ out,
    const float* __restrict__ w3, int b0) {
  __shared__ __align__(16) unsigned short As[128 * 32];
  __shared__ __align__(16) unsigned short Bs[128 * 32];
  int tid = threadIdx.x, wave = tid >> 6, lane = tid & 63;
  int2 sw = swz128();
  int n0 = sw.x, m0 = sw.y;
  int s = b0 + (m0 >> 10);
  float w0 = w3[s * 3];
  float* obase = out + ((size_t)b0 * 1024 + (size_t)m0) * HID + n0;
  const float* cbs = cb + (size_t)s * HID + n0;
  if (w0 == 0.f) {  // write combined-bias base only
    for (int idx = tid; idx < 128 * 32; idx += 256) {
      int rr = idx >> 5, cc = (idx & 31) << 2;
      *(float4*)&obase[(size_t)rr * HID + cc] = *(const float4*)&cbs[cc];
    }
    return;
  }
  const int K = 1024;
  const unsigned short* arow0 = A + (size_t)(m0 + (tid >> 2)) * K + (tid & 3) * 8;
  const unsigned short* arow1 = arow0 + (size_t)64 * K;
  const unsigned short* wrow0 = W + (size_t)(n0 + (tid >> 2)) * K + (tid & 3) * 8;
  const unsigned short* wrow1 = wrow0 + (size_t)64 * K;
  unsigned short* AsW0 = As + wave * 512;
  unsigned short* AsW1 = As + 2048 + wave * 512;
  unsigned short* BsW0 = Bs + wave * 512;
  unsigned short* BsW1 = Bs + 2048 + wave * 512;
  int wm = (wave >> 1) << 6, wn = (wave & 1) << 6;
  int fm = lane & 15, fq = (lane >> 4) << 3;
  f32x4 acc[4][4] = {};
  for (int kb = 0; kb < K; kb += 32) {
    __syncthreads();
    gld16(arow0 + kb, AsW0);
    gld16(arow1 + kb, AsW1);
    gld16(wrow0 + kb, BsW0);
    gld16(wrow1 + kb, BsW1);
    __syncthreads();
    bf16x8 af[4], bfr[4];
#pragma unroll
    for (int i = 0; i < 4; ++i) af[i] = *(const bf16x8*)&As[(wm + i * 16 + fm) * 32 + fq];
#pragma unroll
    for (int j = 0; j < 4; ++j) bfr[j] = *(const bf16x8*)&Bs[(wn + j * 16 + fm) * 32 + fq];
#pragma unroll
    for (int i = 0; i < 4; ++i)
#pragma unroll
      for (int j = 0; j < 4; ++j)
        acc[i][j] = __builtin_amdgcn_mfma_f32_16x16x32_bf16(af[i], bfr[j], acc[i][j], 0, 0, 0);
  }
  int mq = (lane >> 4) << 2;
#pragma unroll
  for (int i = 0; i < 4; ++i) {
#pragma unroll
    for (int j = 0; j < 4; ++j) {
      int n = wn + j * 16 + fm;
      float cbv = cbs[n];
      f32x4 v = acc[i][j];
#pragma unroll
      for (int r = 0; r < 4; ++r)
        obase[(size_t)(wm + i * 16 + mq + r) * HID + n] = w0 * v[r] + cbv;
    }
  }
}

// projP: P = F_e @ W_e  (f32, no bias, no weight) at source-token resolution.
__global__ __launch_bounds__(256) void k_projP(
    const unsigned short* __restrict__ A, const unsigned short* __restrict__ W,
    float* __restrict__ P, const float* __restrict__ w3,
    int b0, int e, int T, int bch, int K) {
  __shared__ __align__(16) unsigned short As[128 * 32];
  __shared__ __align__(16) unsigned short Bs[128 * 32];
  int tid = threadIdx.x, wave = tid >> 6, lane = tid & 63;
  int2 sw = swz128();
  int n0 = sw.x, m0 = sw.y;
  {
    int s0 = m0 / T, s1 = (m0 + 127) / T;
    if (s1 >= bch) s1 = bch - 1;
    bool act = false;
    for (int s = s0; s <= s1; ++s) act |= (w3[(b0 + s) * 3 + e] != 0.f);
    if (!act) return;
  }
  const unsigned short* arow0 = A + (size_t)(m0 + (tid >> 2)) * K + (tid & 3) * 8;
  const unsigned short* arow1 = arow0 + (size_t)64 * K;
  const unsigned short* wrow0 = W + (size_t)(n0 + (tid >> 2)) * K + (tid & 3) * 8;
  const unsigned short* wrow1 = wrow0 + (size_t)64 * K;
  unsigned short* AsW0 = As + wave * 512;
  unsigned short* AsW1 = As + 2048 + wave * 512;
  unsigned short* BsW0 = Bs + wave * 512;
  unsigned short* BsW1 = Bs + 2048 + wave * 512;
  int wm = (wave >> 1) << 6, wn = (wave & 1) << 6;
  int fm = lane & 15, fq = (lane >> 4) << 3;
  f32x4 acc[4][4] = {};
  for (int kb = 0; kb < K; kb += 32) {
    __syncthreads();
    gld16(arow0 + kb, AsW0);
    gld16(arow1 + kb, AsW1);
    gld16(wrow0 + kb, BsW0);
    gld16(wrow1 + kb, BsW1);
    __syncthreads();
    bf16x8 af[4], bfr[4];
#pragma unroll
    for (int i = 0; i < 4; ++i) af[i] = *(const bf16x8*)&As[(wm + i * 16 + fm) * 32 + fq];
#pragma unroll
    for (int j = 0; j < 4; ++j) bfr[j] = *(const bf16x8*)&Bs[(wn + j * 16 + fm) * 32 + fq];
#pragma unroll
    for (int i = 0; i < 4; ++i)
#pragma unroll
      for (int j = 0; j < 4; ++j)
        acc[i][j] = __builtin_amdgcn_mfma_f32_16x16x32_bf16(af[i], bfr[j], acc[i][j], 0, 0, 0);
  }
  int mq = (lane >> 4) << 2;
#pragma unroll
  for (int i = 0; i < 4; ++i) {
#pragma unroll
    for (int j = 0; j < 4; ++j) {
      int n = n0 + wn + j * 16 + fm;
      f32x4 v = acc[i][j];
#pragma unroll
      for (int r = 0; r < 4; ++r)
        P[(size_t)(m0 + wm + i * 16 + mq + r) * HID + n] = v[r];
    }
  }
}

// ---------------------------------------------------------------- combine
// out[s][t][:] += w1*interp1(P1) + w2*interp2(P2). One block per (s,t).
// Sample-chunked XCD swizzle for P-row L2 locality.
__global__ void k_combine(float* __restrict__ out,
                          const float* __restrict__ P1, const float* __restrict__ P2,
                          const int4* __restrict__ st1, const float4* __restrict__ wc1,
                          const int4* __restrict__ st2, const float4* __restrict__ wc2,
                          const float* __restrict__ w3, int b0) {
  int nwg = gridDim.x;  // bch*1024, multiple of 8
  int lin = blockIdx.x;
  int q = nwg >> 3;
  int bt = (lin & 7) * q + (lin >> 3);
  int s = bt >> 10, t = bt & 1023;
  float w1 = w3[(b0 + s) * 3 + 1], w2 = w3[(b0 + s) * 3 + 2];
  int n = threadIdx.x << 2;
  float* op = out + ((size_t)(b0 + s) * 1024 + t) * HID + n;
  float4 acc = *(float4*)op;
  if (w1 != 0.f) {
    int4 si = st1[t]; float4 wc = wc1[t];
    const float* base = P1 + (size_t)s * 576 * HID + n;
    float4 a = *(const float4*)&base[(size_t)si.x * HID];
    float4 b = *(const float4*)&base[(size_t)si.y * HID];
    float4 c = *(const float4*)&base[(size_t)si.z * HID];
    float4 d = *(const float4*)&base[(size_t)si.w * HID];
    acc.x += w1 * (wc.x * a.x + wc.y * b.x + wc.z * c.x + wc.w * d.x);
    acc.y += w1 * (wc.x * a.y + wc.y * b.y + wc.z * c.y + wc.w * d.y);
    acc.z += w1 * (wc.x * a.z + wc.y * b.z + wc.z * c.z + wc.w * d.z);
    acc.w += w1 * (wc.x * a.w + wc.y * b.w + wc.z * c.w + wc.w * d.w);
  }
  if (w2 != 0.f) {
    int4 si = st2[t]; float4 wc = wc2[t];
    const float* base = P2 + (size_t)s * 196 * HID + n;
    float4 a = *(const float4*)&base[(size_t)si.x * HID];
    float4 b = *(const float4*)&base[(size_t)si.y * HID];
    float4 c = *(const float4*)&base[(size_t)si.z * HID];
    float4 d = *(const float4*)&base[(size_t)si.w * HID];
    acc.x += w2 * (wc.x * a.x + wc.y * b.x + wc.z * c.x + wc.w * d.x);
    acc.y += w2 * (wc.x * a.y + wc.y * b.y + wc.z * c.y + wc.w * d.y);
    acc.z += w2 * (wc.x * a.z + wc.y * b.z + wc.z * c.z + wc.w * d.z);
    acc.w += w2 * (wc.x * a.w + wc.y * b.w + wc.z * c.w + wc.w * d.w);
  }
  *(float4*)op = acc;
}

// ---------------------------------------------------------------- launch
extern "C" void kernel_launch(void* const* d_in, const int* in_sizes, int n_in,
                              void* d_out, int out_size, void* d_ws, size_t ws_size,
                              hipStream_t stream) {
  (void)in_sizes; (void)n_in; (void)out_size;
  const float* x = (const float*)d_in[0];
  const int* sel = (const int*)d_in[1];
  const float* rw = (const float*)d_in[2];
  const float* wt[3] = {(const float*)d_in[3], (const float*)d_in[7], (const float*)d_in[11]};
  const float* bt[3] = {(const float*)d_in[4], (const float*)d_in[8], (const float*)d_in[12]};
  const float* wp[3] = {(const float*)d_in[5], (const float*)d_in[9], (const float*)d_in[13]};
  const float* bp[3] = {(const float*)d_in[6], (const float*)d_in[10], (const float*)d_in[14]};
  float* out = (float*)d_out;

  char* ws = (char*)d_ws;
  size_t off = 0;
  auto alloc = [&](size_t bytes) -> void* {
    off = (off + 255) & ~(size_t)255;
    void* p = ws + off;
    off += bytes;
    return p;
  };
  auto ceil128 = [](size_t m) -> size_t { return (m + 127) & ~(size_t)127; };

  float* w3 = (float*)alloc(64 * 3 * 4);
  float* cb = (float*)alloc((size_t)64 * HID * 4);
  int* koff0 = (int*)alloc(608 * 4);
  int* koff1 = (int*)alloc(608 * 4);
  int* koff2 = (int*)alloc(3072 * 4);
  int* ro0 = (int*)alloc((size_t)64 * 1024 * 4);
  int* ro1 = (int*)alloc((size_t)64 * 576 * 4);
  int* ro2 = (int*)alloc((size_t)64 * 196 * 4);
  int4* st1 = (int4*)alloc(1024 * 16);
  float4* wc1 = (float4*)alloc(1024 * 16);
  int4* st2 = (int4*)alloc(1024 * 16);
  float4* wc2 = (float4*)alloc(1024 * 16);
  unsigned short* wt0p = (unsigned short*)alloc((size_t)1024 * 608 * 2);
  unsigned short* wt1p = (unsigned short*)alloc((size_t)768 * 608 * 2);
  unsigned short* wt2p = (unsigned short*)alloc((size_t)1152 * 3072 * 2);
  unsigned short* wp0p = (unsigned short*)alloc((size_t)1024 * 1024 * 2);
  unsigned short* wp1p = (unsigned short*)alloc((size_t)1024 * 768 * 2);
  unsigned short* wp2p = (unsigned short*)alloc((size_t)1024 * 1152 * 2);
  size_t fixed_end = off;

  // scratch (phase-overlapped, ushort elems):
  //  ph0: Ftow0[bc*1024*1024] + Apad0[bc*1024*608]
  //  ph1: x336[bc*338688] + Apad1[Mp1*608] + Ftow1[Mp1*768]
  //  ph2: Apad2[Mp2*3072] + Ftow2[Mp2*1152]
  auto scratch_elems = [&](int bc) -> size_t {
    size_t mp1 = ceil128((size_t)bc * 576), mp2 = ceil128((size_t)bc * 196);
    size_t p0 = (size_t)bc * 1024 * 1024 + (size_t)bc * 1024 * 608;
    size_t p1 = (size_t)bc * 338688 + mp1 * 608 + mp1 * 768;
    size_t p2 = mp2 * 3072 + mp2 * 1152;
    size_t m = p0 > p1 ? p0 : p1;
    return m > p2 ? m : p2;
  };
  auto need = [&](int bc) -> size_t {
    size_t mp1 = ceil128((size_t)bc * 576), mp2 = ceil128((size_t)bc * 196);
    return scratch_elems(bc) * 2 + (mp1 + mp2) * (size_t)HID * 4 + 32 * 512;
  };
  int bch = 64;
  while (bch > 1 && fixed_end + need(bch) > ws_size) bch >>= 1;

  size_t Mp1 = ceil128((size_t)bch * 576), Mp2 = ceil128((size_t)bch * 196);
  unsigned short* scratch = (unsigned short*)alloc(scratch_elems(bch) * 2);
  float* P1 = (float*)alloc(Mp1 * HID * 4);
  float* P2 = (float*)alloc(Mp2 * HID * 4);

  // phase-local aliases into scratch
  unsigned short* Ftow0 = scratch;
  unsigned short* Apad0 = scratch + (size_t)bch * 1024 * 1024;
  unsigned short* x336 = scratch;
  unsigned short* Apad1 = scratch + (size_t)bch * 338688;
  unsigned short* Ftow1 = Apad1 + Mp1 * 608;
  unsigned short* Apad2 = scratch;
  unsigned short* Ftow2 = scratch + Mp2 * 3072;

  // ---- prep
  k_weights<<<1, 64, 0, stream>>>(sel, rw, w3);
  k_cbias<<<64, 256, 0, stream>>>(w3, bp[0], bp[1], bp[2], cb);
  {
    int n0 = max(608, max(bch * 1024, 1024));
    int n1 = max(608, max(bch * 576, 1024));
    int n2 = max(3072, max(bch * 196, 1024));
    k_tables<<<(n0 + 255) / 256, 256, 0, stream>>>(koff0, ro0, st1, wc1, 448, 14, 32, 1024, bch, 588, 608);
    k_tables<<<(n1 + 255) / 256, 256, 0, stream>>>(koff1, ro1, st1, wc1, 336, 14, 24, 576, bch, 588, 608);
    k_tables<<<(n2 + 255) / 256, 256, 0, stream>>>(koff2, ro2, st2, wc2, 448, 32, 14, 196, bch, 3072, 3072);
  }
  k_pack_w<<<dim3(608 / 32, 1024 / 32), 256, 0, stream>>>(wt[0], wt0p, 588, 1024, 608);
  k_pack_w<<<dim3(608 / 32, 768 / 32), 256, 0, stream>>>(wt[1], wt1p, 588, 768, 608);
  k_pack_w<<<dim3(3072 / 32, 1152 / 32), 256, 0, stream>>>(wt[2], wt2p, 3072, 1152, 3072);
  k_pack_w<<<dim3(1024 / 32, 1024 / 32), 256, 0, stream>>>(wp[0], wp0p, 1024, 1024, 1024);
  k_pack_w<<<dim3(768 / 32, 1024 / 32), 256, 0, stream>>>(wp[1], wp1p, 768, 1024, 768);
  k_pack_w<<<dim3(1152 / 32, 1024 / 32), 256, 0, stream>>>(wp[2], wp2p, 1152, 1024, 1152);

  int nchunk = 64 / bch;
  for (int c = 0; c < nchunk; ++c) {
    int b0 = c * bch;
    const float* xc = x + (size_t)b0 * 3 * 448 * 448;

    // ---- Expert 0: im2col -> tower -> proj0 (writes out base = w0*P0 + cb)
    {
      int M = bch * 1024;
      k_im2col_f32<<<dim3(M, 2), 256, 0, stream>>>(xc, Apad0, ro0, koff0, M, 588, 608,
                                                   w3, b0, 0, 1024);
      k_tower<<<dim3(1024 / 128, M / 128), 256, 0, stream>>>(Apad0, wt0p, bt[0], Ftow0,
                                                             1024, 608, w3, b0, 0, 1024, bch);
      k_proj0<<<dim3(HID / 128, M / 128), 256, 0, stream>>>(Ftow0, wp0p, cb, out, w3, b0);
    }
    // ---- Expert 1: resize -> im2col -> tower -> projP
    {
      int tot = bch * 3 * 336 * 336;
      int M = bch * 576;
      k_resize_img<<<(tot + 255) / 256, 256, 0, stream>>>(xc, x336, tot, w3, b0);
      k_im2col_bf16<<<dim3(M, 2), 256, 0, stream>>>(x336, Apad1, ro1, koff1, M, 588, 608,
                                                    w3, b0, 1, 576);
      k_tower<<<dim3(768 / 128, (int)(Mp1 / 128)), 256, 0, stream>>>(
          Apad1, wt1p, bt[1], Ftow1, 768, 608, w3, b0, 1, 576, bch);
      k_projP<<<dim3(HID / 128, (int)(Mp1 / 128)), 256, 0, stream>>>(
          Ftow1, wp1p, P1, w3, b0, 1, 576, bch, 768);
    }
    // ---- Expert 2: im2col -> tower -> projP
    {
      int M = bch * 196;
      k_im2col_f32<<<dim3(M, 6), 256, 0, stream>>>(xc, Apad2, ro2, koff2, M, 3072, 3072,
                                                   w3, b0, 2, 196);
      k_tower<<<dim3(1152 / 128, (int)(Mp2 / 128)), 256, 0, stream>>>(
          Apad2, wt2p, bt[2], Ftow2, 1152, 3072, w3, b0, 2, 196, bch);
      k_projP<<<dim3(HID / 128, (int)(Mp2 / 128)), 256, 0, stream>>>(
          Ftow2, wp2p, P2, w3, b0, 2, 196, bch, 1152);
    }
    // ---- combine: out += w1*interp(P1) + w2*interp(P2)
    k_combine<<<bch * 1024, 256, 0, stream>>>(out, P1, P2, st1, wc1, st2, wc2, w3, b0);
  }
}